// Round 3
// baseline (1564.520 us; speedup 1.0000x reference)
//
#include <hip/hip_runtime.h>
#include <cstdint>

#define F_IN  128
#define F_HID 16
#define F_OUT 138
#define NBUCK 256        // node buckets
#define NPB_SHIFT 9
#define NPB 512          // nodes per bucket (100000/512 -> buckets 0..195 used)
#define NB  256          // edge slabs (= blocks) for the binning passes

// ---------------------------------------------------------------------------
// Detect edge_index dtype: int64 (LE, values < 2^31) -> every odd int32 word
// is zero. flag = 1 -> int64 (stride 2 int32 words), 0 -> int32.
__global__ void k_detect(const int* __restrict__ idx, int* __restrict__ flag) {
    __shared__ int nz;
    if (threadIdx.x == 0) nz = 0;
    __syncthreads();
    for (int i = threadIdx.x; i < 1024; i += blockDim.x)
        if (idx[2 * i + 1] != 0) nz = 1;
    __syncthreads();
    if (threadIdx.x == 0) *flag = (nz == 0) ? 1 : 0;
}

// Pass A: per-block LDS histogram of dst-buckets over this block's edge slab.
__global__ void k_bincount(const int* __restrict__ idx, const int* __restrict__ flag,
                           unsigned* __restrict__ cnt, int E) {
    __shared__ unsigned hist[NBUCK];
    int tid = threadIdx.x;
    for (int i = tid; i < NBUCK; i += 256) hist[i] = 0;
    __syncthreads();
    const int mult = 1 + *flag;
    int slab = (E + NB - 1) / NB;
    int start = blockIdx.x * slab;
    int end = min(E, start + slab);
    if (mult == 2) {
        for (int e = start + tid; e < end; e += 256) {
            int d = ((const int2*)idx)[(size_t)E + e].x;
            atomicAdd(&hist[d >> NPB_SHIFT], 1u);
        }
    } else {
        for (int e = start + tid; e < end; e += 256) {
            int d = idx[(size_t)E + e];
            atomicAdd(&hist[d >> NPB_SHIFT], 1u);
        }
    }
    __syncthreads();
    for (int i = tid; i < NBUCK; i += 256) cnt[(size_t)i * NB + blockIdx.x] = hist[i];
}

// Scan cnt[bucket][block] (bucket-major) -> exclusive global offsets; emits
// bucketPtr[] for downstream kernels. One block, 256 threads (t = bucket).
__global__ void k_scan(unsigned* __restrict__ cnt, unsigned* __restrict__ bucketPtr, int E) {
    __shared__ unsigned tot[NBUCK];
    int t = threadIdx.x;
    unsigned run = 0;
    for (int b = 0; b < NB; ++b) {
        unsigned c = cnt[(size_t)t * NB + b];
        cnt[(size_t)t * NB + b] = run;
        run += c;
    }
    tot[t] = run;
    __syncthreads();
    if (t == 0) {
        unsigned r = 0;
        for (int i = 0; i < NBUCK; ++i) { unsigned c = tot[i]; tot[i] = r; bucketPtr[i] = r; r += c; }
        bucketPtr[NBUCK] = r;   // == E
    }
    __syncthreads();
    unsigned base = tot[t];
    for (int b = 0; b < NB; ++b) cnt[(size_t)t * NB + b] += base;
}

// Pass B: re-read slab, place each edge at its (block,bucket) segment via LDS
// cursors. Packed entry: (dstLocal<<17) | src  (9+17 = 26 bits).
__global__ void k_binfill(const int* __restrict__ idx, const int* __restrict__ flag,
                          const unsigned* __restrict__ cnt,
                          unsigned* __restrict__ binned, int E) {
    __shared__ unsigned cur[NBUCK];
    int tid = threadIdx.x;
    for (int i = tid; i < NBUCK; i += 256) cur[i] = cnt[(size_t)i * NB + blockIdx.x];
    __syncthreads();
    const int mult = 1 + *flag;
    int slab = (E + NB - 1) / NB;
    int start = blockIdx.x * slab;
    int end = min(E, start + slab);
    for (int e = start + tid; e < end; e += 256) {
        int s, d;
        if (mult == 2) { s = ((const int2*)idx)[e].x; d = ((const int2*)idx)[(size_t)E + e].x; }
        else           { s = idx[e];                  d = idx[(size_t)E + e]; }
        unsigned pos = atomicAdd(&cur[d >> NPB_SHIFT], 1u);
        binned[pos] = ((unsigned)(d & (NPB - 1)) << 17) | (unsigned)s;
    }
}

// Degree (and dinv) from the bins: LDS histogram per bucket, zero global atomics.
__global__ void k_deg_dinv(const unsigned* __restrict__ bucketPtr,
                           const unsigned* __restrict__ binned,
                           float* __restrict__ dinv, int n) {
    __shared__ unsigned deg[NPB];
    int tid = threadIdx.x;
    int bb = blockIdx.x;
    for (int i = tid; i < NPB; i += 256) deg[i] = 0;
    __syncthreads();
    unsigned start = bucketPtr[bb], end = bucketPtr[bb + 1];
    for (unsigned i = start + tid; i < end; i += 256)
        atomicAdd(&deg[binned[i] >> 17], 1u);
    __syncthreads();
    int vbase = bb << NPB_SHIFT;
    for (int lv = tid; lv < NPB; lv += 256) {
        int v = vbase + lv;
        if (v < n) dinv[v] = rsqrtf((float)(deg[lv] + 1u));   // +1 self-loop
    }
}

// g1[v][j] = dinv[v] * (x[v] . W1[:,j]).  16 nodes x 16 feats per block.
__global__ void k_gemm1(const float* __restrict__ x, const float* __restrict__ W1,
                        const float* __restrict__ dinv,
                        float* __restrict__ g1, int n) {
    __shared__ float w1s[F_IN * F_HID];     // 8 KB
    __shared__ float xs[16][F_IN + 4];
    int tid = threadIdx.x;
    for (int i = tid; i < F_IN * F_HID; i += 256) w1s[i] = W1[i];
    int nb = blockIdx.x * 16;
    for (int q = tid; q < 512; q += 256) {
        int r = q >> 5, k4 = q & 31;
        int g = nb + r;
        float4 v = make_float4(0.f, 0.f, 0.f, 0.f);
        if (g < n) v = ((const float4*)x)[(size_t)g * 32 + k4];
        xs[r][k4 * 4 + 0] = v.x; xs[r][k4 * 4 + 1] = v.y;
        xs[r][k4 * 4 + 2] = v.z; xs[r][k4 * 4 + 3] = v.w;
    }
    __syncthreads();
    int r = tid >> 4, j = tid & 15;
    int g = nb + r;
    if (g < n) {
        float acc = 0.f;
#pragma unroll
        for (int k = 0; k < F_IN; ++k) acc += xs[r][k] * w1s[k * F_HID + j];
        g1[(size_t)g * F_HID + j] = acc * dinv[g];
    }
}

// Bucketed gather-aggregate into an LDS accumulator. Two blocks per bucket
// (feature halves). Self-loop term is the accumulator init. Fused epilogue:
//   RELU=1: gout = relu(dinv*acc + b1[f]) * dinv   (layer-1 -> g2)
//   RELU=0: gout = dinv*acc                        (layer-2 pre-GEMM)
template <int RELU>
__global__ void __launch_bounds__(512)
k_agg(const unsigned* __restrict__ bucketPtr, const unsigned* __restrict__ binned,
      const float* __restrict__ gin, float* __restrict__ gout,
      const float* __restrict__ dinv, const float* __restrict__ b1, int n) {
    __shared__ float acc[NPB][8];   // 16 KB
    int tid = threadIdx.x;
    int bb = blockIdx.x >> 1;
    int half = blockIdx.x & 1;
    int vbase = bb << NPB_SHIFT;
    for (int q = tid; q < NPB * 8; q += 512) {
        int lv = q >> 3, j = q & 7;
        int v = vbase + lv;
        acc[lv][j] = (v < n) ? gin[(size_t)v * F_HID + half * 8 + j] : 0.f;
    }
    __syncthreads();
    unsigned start = bucketPtr[bb], end = bucketPtr[bb + 1];
    int eg = tid >> 3, j = tid & 7;
    for (unsigned i = start + eg; i < end; i += 64) {
        unsigned entry = binned[i];
        int src = (int)(entry & 0x1FFFFu);
        int dl  = (int)(entry >> 17);
        atomicAdd(&acc[dl][j], gin[(size_t)src * F_HID + half * 8 + j]);
    }
    __syncthreads();
    for (int q = tid; q < NPB * 8; q += 512) {
        int lv = q >> 3, j = q & 7;
        int v = vbase + lv;
        if (v < n) {
            float di = dinv[v];
            int f = half * 8 + j;
            float a = acc[lv][j];
            if (RELU) gout[(size_t)v * F_HID + f] = fmaxf(di * a + b1[f], 0.f) * di;
            else      gout[(size_t)v * F_HID + f] = di * a;
        }
    }
}

// out[v][c] = B[v] . W2[:,c] + b2[c]   (dinv already folded into B)
__global__ void k_out(const float* __restrict__ B,
                      const float* __restrict__ W2, const float* __restrict__ b2,
                      float* __restrict__ out, int n) {
    __shared__ float w2s[F_HID * F_OUT];
    __shared__ float b2s[F_OUT];
    int tid = threadIdx.x;
    for (int i = tid; i < F_HID * F_OUT; i += 256) w2s[i] = W2[i];
    if (tid < F_OUT) b2s[tid] = b2[tid];
    __syncthreads();
    int total = n * F_OUT;
    int stride = gridDim.x * blockDim.x;
    for (int i = blockIdx.x * blockDim.x + tid; i < total; i += stride) {
        int node = i / F_OUT, c = i - node * F_OUT;
        float acc = 0.f;
#pragma unroll
        for (int j = 0; j < F_HID; ++j) acc += B[(size_t)node * F_HID + j] * w2s[j * F_OUT + c];
        out[i] = acc + b2s[c];
    }
}

extern "C" void kernel_launch(void* const* d_in, const int* in_sizes, int n_in,
                              void* d_out, int out_size, void* d_ws, size_t ws_size,
                              hipStream_t stream) {
    const float* x   = (const float*)d_in[0];
    const int*   idx = (const int*)d_in[1];
    const float* W1  = (const float*)d_in[2];
    const float* b1  = (const float*)d_in[3];
    const float* W2  = (const float*)d_in[4];
    const float* b2  = (const float*)d_in[5];
    float* out = (float*)d_out;

    const int n = in_sizes[0] / F_IN;       // 100000
    const int E = in_sizes[1] / 2;          // 6400000

    char* ws = (char*)d_ws;
    size_t off = 0;
    auto carve = [&](size_t bytes) { char* p = ws + off; off += (bytes + 255) / 256 * 256; return p; };
    int*      flag      = (int*)carve(4);
    float*    dinv      = (float*)carve((size_t)n * 4);
    unsigned* bucketPtr = (unsigned*)carve((NBUCK + 1) * 4);
    unsigned* cnt       = (unsigned*)carve((size_t)NBUCK * NB * 4);  // 256 KB
    float*    buf1      = (float*)carve((size_t)n * F_HID * 4);
    float*    buf2      = (float*)carve((size_t)n * F_HID * 4);
    // binned edge list lives in d_out (25.6 MB <= 55.2 MB); fully consumed
    // by k_agg<0> before k_out writes d_out.
    unsigned* binned = (unsigned*)d_out;

    const int B = 256;
    k_detect  <<<1, B, 0, stream>>>(idx, flag);
    k_bincount<<<NB, B, 0, stream>>>(idx, flag, cnt, E);
    k_scan    <<<1, NBUCK, 0, stream>>>(cnt, bucketPtr, E);
    k_binfill <<<NB, B, 0, stream>>>(idx, flag, cnt, binned, E);
    k_deg_dinv<<<NBUCK, B, 0, stream>>>(bucketPtr, binned, dinv, n);
    k_gemm1   <<<(n + 15) / 16, B, 0, stream>>>(x, W1, dinv, buf1, n);
    k_agg<1>  <<<NBUCK * 2, 512, 0, stream>>>(bucketPtr, binned, buf1, buf2, dinv, b1, n);
    k_agg<0>  <<<NBUCK * 2, 512, 0, stream>>>(bucketPtr, binned, buf2, buf1, dinv, b1, n);
    k_out     <<<8192, B, 0, stream>>>(buf1, W2, b2, out, n);
}

// Round 4
// 1419.658 us; speedup vs baseline: 1.1020x; 1.1020x over previous
//
#include <hip/hip_runtime.h>
#include <cstdint>

#define F_IN  128
#define F_HID 16
#define F_OUT 138
#define NBUCK 256        // node buckets
#define NPB_SHIFT 9
#define NPB 512          // nodes per bucket
#define NB  256          // edge slabs (= blocks) for binning passes
#define EPB 8            // edge-split sub-blocks per bucket in k_agg

// ---------------------------------------------------------------------------
// Detect edge_index dtype: int64 (LE, values < 2^31) -> every odd int32 word
// is zero. flag = 1 -> int64 (stride 2 int32 words), 0 -> int32.
__global__ void k_detect(const int* __restrict__ idx, int* __restrict__ flag) {
    __shared__ int nz;
    if (threadIdx.x == 0) nz = 0;
    __syncthreads();
    for (int i = threadIdx.x; i < 1024; i += blockDim.x)
        if (idx[2 * i + 1] != 0) nz = 1;
    __syncthreads();
    if (threadIdx.x == 0) *flag = (nz == 0) ? 1 : 0;
}

// Pass A: per-block LDS histogram of dst-buckets over this block's edge slab.
__global__ void k_bincount(const int* __restrict__ idx, const int* __restrict__ flag,
                           unsigned* __restrict__ cnt, int E) {
    __shared__ unsigned hist[NBUCK];
    int tid = threadIdx.x;
    for (int i = tid; i < NBUCK; i += 256) hist[i] = 0;
    __syncthreads();
    const int mult = 1 + *flag;
    int slab = (E + NB - 1) / NB;
    int start = blockIdx.x * slab;
    int end = min(E, start + slab);
    if (mult == 2) {
        for (int e = start + tid; e < end; e += 256) {
            int d = ((const int2*)idx)[(size_t)E + e].x;
            atomicAdd(&hist[d >> NPB_SHIFT], 1u);
        }
    } else {
        for (int e = start + tid; e < end; e += 256) {
            int d = idx[(size_t)E + e];
            atomicAdd(&hist[d >> NPB_SHIFT], 1u);
        }
    }
    __syncthreads();
    for (int i = tid; i < NBUCK; i += 256) cnt[(size_t)i * NB + blockIdx.x] = hist[i];
}

// Scan cnt[bucket][block] (bucket-major) -> exclusive global offsets + bucketPtr.
__global__ void k_scan(unsigned* __restrict__ cnt, unsigned* __restrict__ bucketPtr, int E) {
    __shared__ unsigned tot[NBUCK];
    int t = threadIdx.x;
    unsigned run = 0;
    for (int b = 0; b < NB; ++b) {
        unsigned c = cnt[(size_t)t * NB + b];
        cnt[(size_t)t * NB + b] = run;
        run += c;
    }
    tot[t] = run;
    __syncthreads();
    if (t == 0) {
        unsigned r = 0;
        for (int i = 0; i < NBUCK; ++i) { unsigned c = tot[i]; tot[i] = r; bucketPtr[i] = r; r += c; }
        bucketPtr[NBUCK] = r;   // == E
    }
    __syncthreads();
    unsigned base = tot[t];
    for (int b = 0; b < NB; ++b) cnt[(size_t)t * NB + b] += base;
}

// Pass B: re-read slab, place each edge in its (block,bucket) segment via LDS
// cursors. Packed entry: (dstLocal<<17) | src  (9+17 = 26 bits).
__global__ void k_binfill(const int* __restrict__ idx, const int* __restrict__ flag,
                          const unsigned* __restrict__ cnt,
                          unsigned* __restrict__ binned, int E) {
    __shared__ unsigned cur[NBUCK];
    int tid = threadIdx.x;
    for (int i = tid; i < NBUCK; i += 256) cur[i] = cnt[(size_t)i * NB + blockIdx.x];
    __syncthreads();
    const int mult = 1 + *flag;
    int slab = (E + NB - 1) / NB;
    int start = blockIdx.x * slab;
    int end = min(E, start + slab);
    for (int e = start + tid; e < end; e += 256) {
        int s, d;
        if (mult == 2) { s = ((const int2*)idx)[e].x; d = ((const int2*)idx)[(size_t)E + e].x; }
        else           { s = idx[e];                  d = idx[(size_t)E + e]; }
        unsigned pos = atomicAdd(&cur[d >> NPB_SHIFT], 1u);
        binned[pos] = ((unsigned)(d & (NPB - 1)) << 17) | (unsigned)s;
    }
}

// Degree (and dinv) from the bins: LDS histogram per bucket, zero global atomics.
__global__ void k_deg_dinv(const unsigned* __restrict__ bucketPtr,
                           const unsigned* __restrict__ binned,
                           float* __restrict__ dinv, int n) {
    __shared__ unsigned deg[NPB];
    int tid = threadIdx.x;
    int bb = blockIdx.x;
    for (int i = tid; i < NPB; i += 256) deg[i] = 0;
    __syncthreads();
    unsigned start = bucketPtr[bb], end = bucketPtr[bb + 1];
    for (unsigned i = start + tid; i < end; i += 256)
        atomicAdd(&deg[binned[i] >> 17], 1u);
    __syncthreads();
    int vbase = bb << NPB_SHIFT;
    for (int lv = tid; lv < NPB; lv += 256) {
        int v = vbase + lv;
        if (v < n) dinv[v] = rsqrtf((float)(deg[lv] + 1u));   // +1 self-loop
    }
}

// g1[v][j] = dinv[v] * (x[v] . W1[:,j]); written to buf1 (gather source) AND
// buf2 (accumulator init = self-loop term).
__global__ void k_gemm1(const float* __restrict__ x, const float* __restrict__ W1,
                        const float* __restrict__ dinv,
                        float* __restrict__ g1, float* __restrict__ ginit, int n) {
    __shared__ float w1s[F_IN * F_HID];     // 8 KB
    __shared__ float xs[16][F_IN + 4];
    int tid = threadIdx.x;
    for (int i = tid; i < F_IN * F_HID; i += 256) w1s[i] = W1[i];
    int nb = blockIdx.x * 16;
    for (int q = tid; q < 512; q += 256) {
        int r = q >> 5, k4 = q & 31;
        int g = nb + r;
        float4 v = make_float4(0.f, 0.f, 0.f, 0.f);
        if (g < n) v = ((const float4*)x)[(size_t)g * 32 + k4];
        xs[r][k4 * 4 + 0] = v.x; xs[r][k4 * 4 + 1] = v.y;
        xs[r][k4 * 4 + 2] = v.z; xs[r][k4 * 4 + 3] = v.w;
    }
    __syncthreads();
    int r = tid >> 4, j = tid & 15;
    int g = nb + r;
    if (g < n) {
        float acc = 0.f;
#pragma unroll
        for (int k = 0; k < F_IN; ++k) acc += xs[r][k] * w1s[k * F_HID + j];
        float v = acc * dinv[g];
        size_t o = (size_t)g * F_HID + j;
        g1[o] = v;
        ginit[o] = v;
    }
}

// Bucketed gather-aggregate. EPB sub-blocks per bucket, each handles a
// contiguous chunk of the bucket's edges: 16 lanes/edge read the FULL
// gin[src] row (one 64B line), LDS-atomic into acc[512][17], then flush
// partials into gacc (pre-initialized with the self-loop term) via global
// atomicAdd.
__global__ void __launch_bounds__(512, 1)
k_agg(const unsigned* __restrict__ bucketPtr, const unsigned* __restrict__ binned,
      const float* __restrict__ gin, float* __restrict__ gacc, int n) {
    __shared__ float acc[NPB][F_HID + 1];   // pad 17 -> 34.8 KB, 4 blocks/CU
    int tid = threadIdx.x;
    int bb = blockIdx.x / EPB;
    int sb = blockIdx.x - bb * EPB;
    unsigned start = bucketPtr[bb], end = bucketPtr[bb + 1];
    unsigned cnt = end - start;
    if (cnt == 0) return;
    for (int q = tid; q < NPB * F_HID; q += 512)
        acc[q >> 4][q & 15] = 0.f;
    __syncthreads();
    // contiguous chunk for this sub-block
    unsigned chunk = (cnt + EPB - 1) / EPB;
    unsigned cs = start + sb * chunk;
    unsigned ce = min(end, cs + chunk);
    int j = tid & 15;
    for (unsigned i = cs + (tid >> 4); i < ce; i += 32) {
        unsigned entry = binned[i];
        int src = (int)(entry & 0x1FFFFu);
        int dl  = (int)(entry >> 17);
        atomicAdd(&acc[dl][j], gin[(size_t)src * F_HID + j]);
    }
    __syncthreads();
    int vbase = bb << NPB_SHIFT;
    for (int q = tid; q < NPB * F_HID; q += 512) {
        float a = acc[q >> 4][q & 15];
        int v = vbase + (q >> 4);
        if (a != 0.f && v < n)
            atomicAdd(&gacc[(size_t)v * F_HID + (q & 15)], a);
    }
}

// Epilogues. RELU=1 (after layer-1 agg): g2 = relu(dinv*acc + b1)*dinv,
// written to both gout (gather src) and ginit (layer-2 accumulator init).
// RELU=0 (after layer-2 agg): gout = dinv*acc (feeds k_out).
template <int RELU>
__global__ void k_epi(const float* __restrict__ gacc, const float* __restrict__ dinv,
                      const float* __restrict__ b1,
                      float* __restrict__ gout, float* __restrict__ ginit, int n) {
    int i = blockIdx.x * blockDim.x + threadIdx.x;
    if (i < n * F_HID) {
        int v = i >> 4, j = i & 15;
        float di = dinv[v];
        if (RELU) {
            float h = fmaxf(di * gacc[i] + b1[j], 0.f) * di;
            gout[i] = h;
            ginit[i] = h;
        } else {
            gout[i] = di * gacc[i];
        }
    }
}

// out[v][c] = B[v] . W2[:,c] + b2[c]   (dinv already folded into B)
__global__ void k_out(const float* __restrict__ B,
                      const float* __restrict__ W2, const float* __restrict__ b2,
                      float* __restrict__ out, int n) {
    __shared__ float w2s[F_HID * F_OUT];
    __shared__ float b2s[F_OUT];
    int tid = threadIdx.x;
    for (int i = tid; i < F_HID * F_OUT; i += 256) w2s[i] = W2[i];
    if (tid < F_OUT) b2s[tid] = b2[tid];
    __syncthreads();
    int total = n * F_OUT;
    int stride = gridDim.x * blockDim.x;
    for (int i = blockIdx.x * blockDim.x + tid; i < total; i += stride) {
        int node = i / F_OUT, c = i - node * F_OUT;
        float acc = 0.f;
#pragma unroll
        for (int j = 0; j < F_HID; ++j) acc += B[(size_t)node * F_HID + j] * w2s[j * F_OUT + c];
        out[i] = acc + b2s[c];
    }
}

extern "C" void kernel_launch(void* const* d_in, const int* in_sizes, int n_in,
                              void* d_out, int out_size, void* d_ws, size_t ws_size,
                              hipStream_t stream) {
    const float* x   = (const float*)d_in[0];
    const int*   idx = (const int*)d_in[1];
    const float* W1  = (const float*)d_in[2];
    const float* b1  = (const float*)d_in[3];
    const float* W2  = (const float*)d_in[4];
    const float* b2  = (const float*)d_in[5];
    float* out = (float*)d_out;

    const int n = in_sizes[0] / F_IN;       // 100000
    const int E = in_sizes[1] / 2;          // 6400000

    char* ws = (char*)d_ws;
    size_t off = 0;
    auto carve = [&](size_t bytes) { char* p = ws + off; off += (bytes + 255) / 256 * 256; return p; };
    int*      flag      = (int*)carve(4);
    float*    dinv      = (float*)carve((size_t)n * 4);
    unsigned* bucketPtr = (unsigned*)carve((NBUCK + 1) * 4);
    unsigned* cnt       = (unsigned*)carve((size_t)NBUCK * NB * 4);  // 256 KB
    float*    buf1      = (float*)carve((size_t)n * F_HID * 4);      // gather src
    float*    buf2      = (float*)carve((size_t)n * F_HID * 4);      // accumulator
    // binned edge list lives in d_out (25.6 MB <= 55.2 MB); fully consumed
    // by the second k_agg before k_out writes d_out.
    unsigned* binned = (unsigned*)d_out;

    const int B = 256;
    const int nbEpi = (n * F_HID + B - 1) / B;
    k_detect  <<<1, B, 0, stream>>>(idx, flag);
    k_bincount<<<NB, B, 0, stream>>>(idx, flag, cnt, E);
    k_scan    <<<1, NBUCK, 0, stream>>>(cnt, bucketPtr, E);
    k_binfill <<<NB, B, 0, stream>>>(idx, flag, cnt, binned, E);
    k_deg_dinv<<<NBUCK, B, 0, stream>>>(bucketPtr, binned, dinv, n);
    k_gemm1   <<<(n + 15) / 16, B, 0, stream>>>(x, W1, dinv, buf1, buf2, n);
    k_agg     <<<NBUCK * EPB, 512, 0, stream>>>(bucketPtr, binned, buf1, buf2, n);
    k_epi<1>  <<<nbEpi, B, 0, stream>>>(buf2, dinv, b1, buf1, buf2, n);
    k_agg     <<<NBUCK * EPB, 512, 0, stream>>>(bucketPtr, binned, buf1, buf2, n);
    k_epi<0>  <<<nbEpi, B, 0, stream>>>(buf2, dinv, b1, buf1, buf1, n);
    k_out     <<<8192, B, 0, stream>>>(buf1, W2, b2, out, n);
}